// Round 1
// baseline (80.118 us; speedup 1.0000x reference)
//
#include <hip/hip_runtime.h>
#include <math.h>

#define NROWS 8400
#define NTOT  8402

__device__ __forceinline__ float sigmoidf_(float x) {
    return 1.0f / (1.0f + expf(-x));
}

__global__ void detect_kernel(const float* __restrict__ cls0, const float* __restrict__ cls1,
                              const float* __restrict__ cls2,
                              const float* __restrict__ box0, const float* __restrict__ box1,
                              const float* __restrict__ box2,
                              const float* __restrict__ obj0, const float* __restrict__ obj1,
                              const float* __restrict__ obj2,
                              float* __restrict__ out, unsigned long long* __restrict__ ws)
{
    const int r = blockIdx.x * blockDim.x + threadIdx.x;

    if (r < NTOT) {
        float val = -1.0f;
        int ok = 0;
        if (r >= NROWS) {
            // sentinel rows: class-0 score 0.47 / 0.46, always eligible
            val = (r == NROWS) ? 0.47f : 0.46f;
            ok = 1;
        } else {
            const float* cls; const float* obj; int hw, n;
            if (r < 6400)      { cls = cls0; obj = obj0; hw = 6400; n = r;        }
            else if (r < 8000) { cls = cls1; obj = obj1; hw = 1600; n = r - 6400; }
            else               { cls = cls2; obj = obj2; hw = 400;  n = r - 8000; }
            // per-row max/argmax on raw logits (sigmoid monotonic); strict > keeps first index
            float m = cls[n];
            int mi = 0;
            #pragma unroll 8
            for (int c = 1; c < 80; ++c) {
                float v = cls[c * hw + n];
                if (v > m) { m = v; mi = c; }
            }
            float sc = sigmoidf_(obj[n]) * sigmoidf_(m);
            if (mi == 0 && sc > 0.1f) { val = sc; ok = 1; }
        }
        if (ok) {
            // positive floats: bit pattern is order-preserving; low word inverted idx -> ties pick smaller idx
            unsigned long long key =
                (((unsigned long long)__float_as_uint(val)) << 32) |
                (unsigned long long)(0xFFFFFFFFu - (unsigned)r);
            atomicMax(ws, key);   // device-scope by default on CDNA
        }
    }

    __syncthreads();
    __threadfence();
    if (threadIdx.x == 0) {
        unsigned int done = atomicAdd((unsigned int*)(ws + 1), 1u);
        if (done == gridDim.x - 1) {
            // last block: everyone's atomicMax is globally visible now
            unsigned long long key = atomicAdd(ws, 0ULL);   // coherent device-scope read
            unsigned int ridx = 0xFFFFFFFFu - (unsigned)(key & 0xFFFFFFFFu);
            float score = __uint_as_float((unsigned)(key >> 32));
            float b0, b1, b2, b3;
            if (ridx >= NROWS) {
                if (ridx == NROWS) { b0 = 0.0f;   b1 = 0.0f;   b2 = 640.0f; b3 = 640.0f; }
                else               { b0 = 320.0f; b1 = 320.0f; b2 = 540.0f; b3 = 540.0f; }
            } else {
                const float* boxp; int hw, n, W; float s;
                if (ridx < 6400)      { boxp = box0; hw = 6400; n = ridx;        W = 80; s = 8.0f;  }
                else if (ridx < 8000) { boxp = box1; hw = 1600; n = ridx - 6400; W = 40; s = 16.0f; }
                else                  { boxp = box2; hw = 400;  n = ridx - 8000; W = 20; s = 32.0f; }
                float bx = boxp[n];
                float by = boxp[hw + n];
                float bw = boxp[2 * hw + n];
                float bh = boxp[3 * hw + n];
                float gx = (float)(n % W);
                float gy = (float)(n / W);
                float cx = (bx + gx) * s;
                float cy = (by + gy) * s;
                float ww = expf(bw) * s;
                float hh = expf(bh) * s;
                b0 = cx - ww * 0.5f;
                b1 = cy - hh * 0.5f;
                b2 = cx + ww * 0.5f;
                b3 = cy + hh * 0.5f;
            }
            out[0] = b0; out[1] = b1; out[2] = b2; out[3] = b3; out[4] = score;
        }
    }
}

extern "C" void kernel_launch(void* const* d_in, const int* in_sizes, int n_in,
                              void* d_out, int out_size, void* d_ws, size_t ws_size,
                              hipStream_t stream) {
    const float* cls0 = (const float*)d_in[0];
    const float* cls1 = (const float*)d_in[1];
    const float* cls2 = (const float*)d_in[2];
    const float* box0 = (const float*)d_in[3];
    const float* box1 = (const float*)d_in[4];
    const float* box2 = (const float*)d_in[5];
    const float* obj0 = (const float*)d_in[6];
    const float* obj1 = (const float*)d_in[7];
    const float* obj2 = (const float*)d_in[8];
    float* out = (float*)d_out;
    unsigned long long* ws = (unsigned long long*)d_ws;

    // ws[0] = argmax key (u64), ws[1] low 4B = block-completion counter
    hipMemsetAsync(d_ws, 0, 16, stream);

    const int block = 256;
    const int grid = (NTOT + block - 1) / block;   // 33 blocks
    detect_kernel<<<grid, block, 0, stream>>>(cls0, cls1, cls2,
                                              box0, box1, box2,
                                              obj0, obj1, obj2,
                                              out, ws);
}

// Round 2
// 79.951 us; speedup vs baseline: 1.0021x; 1.0021x over previous
//
#include <hip/hip_runtime.h>
#include <math.h>

#define NROWS 8400
#define NQ    2100   // NROWS/4 quads; level bases 0/6400/8000 are all %4==0

__device__ __forceinline__ float sigmoidf_(float x) {
    return 1.0f / (1.0f + expf(-x));
}

__global__ void __launch_bounds__(256)
detect_kernel(const float* __restrict__ cls0, const float* __restrict__ cls1,
              const float* __restrict__ cls2,
              const float* __restrict__ box0, const float* __restrict__ box1,
              const float* __restrict__ box2,
              const float* __restrict__ obj0, const float* __restrict__ obj1,
              const float* __restrict__ obj2,
              float* __restrict__ out, unsigned long long* __restrict__ ws)
{
    // block: x = 64 pixel-quads, y = 4 class groups (classes y, y+4, ..., 76)
    const int tx = threadIdx.x;
    const int ty = threadIdx.y;
    const int q  = blockIdx.x * 64 + tx;          // global quad index
    const bool valid = (q < NQ);

    __shared__ float4 smem[4][64];

    const float* cls = nullptr; const float* obj = nullptr; int hw = 0, n = 0;
    if (valid) {
        if (q < 1600)      { cls = cls0; obj = obj0; hw = 6400; n = 4 * q;        }
        else if (q < 2000) { cls = cls1; obj = obj1; hw = 1600; n = 4 * q - 6400; }
        else               { cls = cls2; obj = obj2; hw = 400;  n = 4 * q - 8000; }
    }

    float4 m   = make_float4(-INFINITY, -INFINITY, -INFINITY, -INFINITY);
    float4 c0q = m;
    if (valid) {
        // first class of this group (c = ty); for ty==0 this IS class 0 -> save it
        const float4* p = reinterpret_cast<const float4*>(cls + (size_t)ty * hw + n);
        m = *p;
        if (ty == 0) c0q = m;
        #pragma unroll
        for (int c = ty + 4; c < 80; c += 4) {
            float4 v = *reinterpret_cast<const float4*>(cls + (size_t)c * hw + n);
            m.x = fmaxf(m.x, v.x); m.y = fmaxf(m.y, v.y);
            m.z = fmaxf(m.z, v.z); m.w = fmaxf(m.w, v.w);
        }
    }
    smem[ty][tx] = m;
    __syncthreads();

    if (ty == 0 && valid) {
        float4 m1 = smem[1][tx], m2 = smem[2][tx], m3 = smem[3][tx];
        m.x = fmaxf(fmaxf(m.x, m1.x), fmaxf(m2.x, m3.x));
        m.y = fmaxf(fmaxf(m.y, m1.y), fmaxf(m2.y, m3.y));
        m.z = fmaxf(fmaxf(m.z, m1.z), fmaxf(m2.z, m3.z));
        m.w = fmaxf(fmaxf(m.w, m1.w), fmaxf(m2.w, m3.w));
        // argmax==0  <=>  cls[0] == max over all classes (first-index tie-break)
        float4 o = *reinterpret_cast<const float4*>(obj + n);
        const float mm[4] = { m.x, m.y, m.z, m.w };
        const float c0[4] = { c0q.x, c0q.y, c0q.z, c0q.w };
        const float ov[4] = { o.x, o.y, o.z, o.w };
        #pragma unroll
        for (int i = 0; i < 4; ++i) {
            if (mm[i] == c0[i]) {
                float sc = sigmoidf_(ov[i]) * sigmoidf_(c0[i]);
                if (sc > 0.1f) {
                    unsigned r = 4u * (unsigned)q + (unsigned)i;
                    unsigned long long key =
                        (((unsigned long long)__float_as_uint(sc)) << 32) |
                        (unsigned long long)(0xFFFFFFFFu - r);
                    atomicMax(ws, key);
                }
            }
        }
    }

    // sentinel rows: 0.47@8400 always beats 0.46@8401
    if (blockIdx.x == 0 && tx == 0 && ty == 0) {
        unsigned long long skey =
            (((unsigned long long)__float_as_uint(0.47f)) << 32) |
            (unsigned long long)(0xFFFFFFFFu - (unsigned)NROWS);
        atomicMax(ws, skey);
    }

    __syncthreads();
    __threadfence();
    if (tx == 0 && ty == 0) {
        unsigned int done = atomicAdd((unsigned int*)(ws + 1), 1u);
        if (done == gridDim.x - 1) {
            unsigned long long key = atomicAdd(ws, 0ULL);   // device-coherent read
            unsigned int ridx = 0xFFFFFFFFu - (unsigned)(key & 0xFFFFFFFFu);
            float score = __uint_as_float((unsigned)(key >> 32));
            float b0, b1, b2, b3;
            if (ridx >= NROWS) {
                if (ridx == NROWS) { b0 = 0.0f;   b1 = 0.0f;   b2 = 640.0f; b3 = 640.0f; }
                else               { b0 = 320.0f; b1 = 320.0f; b2 = 540.0f; b3 = 540.0f; }
            } else {
                const float* boxp; int bhw, bn, W; float s;
                if (ridx < 6400)      { boxp = box0; bhw = 6400; bn = ridx;        W = 80; s = 8.0f;  }
                else if (ridx < 8000) { boxp = box1; bhw = 1600; bn = ridx - 6400; W = 40; s = 16.0f; }
                else                  { boxp = box2; bhw = 400;  bn = ridx - 8000; W = 20; s = 32.0f; }
                float bx = boxp[bn];
                float by = boxp[bhw + bn];
                float bw = boxp[2 * bhw + bn];
                float bh = boxp[3 * bhw + bn];
                float gx = (float)(bn % W);
                float gy = (float)(bn / W);
                float cx = (bx + gx) * s;
                float cy = (by + gy) * s;
                float wwv = expf(bw) * s;
                float hhv = expf(bh) * s;
                b0 = cx - wwv * 0.5f;
                b1 = cy - hhv * 0.5f;
                b2 = cx + wwv * 0.5f;
                b3 = cy + hhv * 0.5f;
            }
            out[0] = b0; out[1] = b1; out[2] = b2; out[3] = b3; out[4] = score;
        }
    }
}

extern "C" void kernel_launch(void* const* d_in, const int* in_sizes, int n_in,
                              void* d_out, int out_size, void* d_ws, size_t ws_size,
                              hipStream_t stream) {
    const float* cls0 = (const float*)d_in[0];
    const float* cls1 = (const float*)d_in[1];
    const float* cls2 = (const float*)d_in[2];
    const float* box0 = (const float*)d_in[3];
    const float* box1 = (const float*)d_in[4];
    const float* box2 = (const float*)d_in[5];
    const float* obj0 = (const float*)d_in[6];
    const float* obj1 = (const float*)d_in[7];
    const float* obj2 = (const float*)d_in[8];
    float* out = (float*)d_out;
    unsigned long long* ws = (unsigned long long*)d_ws;

    // ws[0] = argmax key (u64), ws[1] low 4B = block-completion counter
    hipMemsetAsync(d_ws, 0, 16, stream);

    dim3 block(64, 4);
    const int grid = (NQ + 63) / 64;   // 33 blocks
    detect_kernel<<<grid, block, 0, stream>>>(cls0, cls1, cls2,
                                              box0, box1, box2,
                                              obj0, obj1, obj2,
                                              out, ws);
}